// Round 6
// baseline (429.371 us; speedup 1.0000x reference)
//
#include <hip/hip_runtime.h>
#include <math.h>

#define EPSF 1e-7f
#define MAXN 10.0f

typedef unsigned short ushortT;
typedef __bf16 bf16_8 __attribute__((ext_vector_type(8)));
typedef float f32_16 __attribute__((ext_vector_type(16)));

#define MFMA32 __builtin_amdgcn_mfma_f32_32x32x16_bf16
#define BAR asm volatile("s_barrier" ::: "memory")

__device__ __forceinline__ float sinh_div_f(float d) {
    float ds = fmaxf(d, 1e-6f);
    return (d < 1e-6f) ? 1.0f : sinhf(ds) / ds;
}
__device__ __forceinline__ float div_sinh_f(float d) {
    float ds = fmaxf(d, 1e-6f);
    return (d < 1e-6f) ? 1.0f : ds / sinhf(ds);
}
__device__ __forceinline__ float wred(float v) {
#pragma unroll
    for (int off = 32; off > 0; off >>= 1) v += __shfl_xor(v, off, 64);
    return v;
}
// f32 -> bf16(hi) + bf16(lo), both RNE
__device__ __forceinline__ void bsplit(float x, ushortT& h, ushortT& l) {
    unsigned u = __float_as_uint(x);
    unsigned r = (u + 0x7fffu + ((u >> 16) & 1u)) >> 16;
    h = (ushortT)r;
    float lo = x - __uint_as_float(r << 16);
    unsigned ul = __float_as_uint(lo);
    l = (ushortT)((ul + 0x7fffu + ((ul >> 16) & 1u)) >> 16);
}
__device__ __forceinline__ void gload_lds16(const void* g, void* l) {
    __builtin_amdgcn_global_load_lds(
        (const __attribute__((address_space(1))) unsigned int*)g,
        (__attribute__((address_space(3))) unsigned int*)l, 16, 0, 0);
}
// LDS fragment read; physical slot = ((lh<<1)|kk) ^ ((row>>1)&3)  [bit-swapped so the
// half-wave selector lands in slot BIT1 -> lanes l and l+32 hit bank-quads differing
// in bit1, killing the v5 half-wave pairing conflict]
__device__ __forceinline__ bf16_8 fragld(const ushortT* p, int row, int kk, int lh) {
    int slot = ((lh << 1) | kk) ^ ((row >> 1) & 3);
    return *reinterpret_cast<const bf16_8*>(&p[row * 32 + slot * 8]);
}

// ---------------- weight split ----------------
__global__ void split_kernel(const float* __restrict__ x, ushortT* __restrict__ hi,
                             ushortT* __restrict__ lo, int n4) {
    int idx = blockIdx.x * blockDim.x + threadIdx.x;
    if (idx >= n4) return;
    float4 v = reinterpret_cast<const float4*>(x)[idx];
    float f[4] = {v.x, v.y, v.z, v.w};
    ushortT hh[4], ll[4];
#pragma unroll
    for (int e = 0; e < 4; ++e) bsplit(f[e], hh[e], ll[e]);
    reinterpret_cast<ushort4*>(hi)[idx] = ushort4{hh[0], hh[1], hh[2], hh[3]};
    reinterpret_cast<ushort4*>(lo)[idx] = ushort4{ll[0], ll[1], ll[2], ll[3]};
}

// ---------------- prep: z_h -> clamped tangent planes (rows of 256) ----------------
__global__ void prep_kernel(const float* __restrict__ z, ushortT* __restrict__ th,
                            ushortT* __restrict__ tl, int N) {
    int gw = (blockIdx.x * blockDim.x + threadIdx.x) >> 6;
    int lane = threadIdx.x & 63;
    if (gw >= N) return;
    float4 zv = reinterpret_cast<const float4*>(z + (size_t)gw * 256)[lane];
    float z0 = __shfl(zv.x, 0, 64);
    float x0 = fmaxf(z0, 1.f + EPSF);
    float d = acoshf(x0);
    float f = div_sinh_f(d);
    float vx = (lane == 0) ? 0.f : zv.x * f;
    float vy = zv.y * f, vz = zv.z * f, vw = zv.w * f;
    float ss = wred(vx * vx + vy * vy + vz * vz + vw * vw);
    float n = sqrtf(ss);
    float s = fminf(1.f, MAXN / fmaxf(n, EPSF));
    float o[4] = {vx * s, vy * s, vz * s, vw * s};
    ushortT hh[4], ll[4];
#pragma unroll
    for (int e = 0; e < 4; ++e) bsplit(o[e], hh[e], ll[e]);
    reinterpret_cast<ushort4*>(th + (size_t)gw * 256)[lane] = ushort4{hh[0], hh[1], hh[2], hh[3]};
    reinterpret_cast<ushort4*>(tl + (size_t)gw * 256)[lane] = ushort4{ll[0], ll[1], ll[2], ll[3]};
}

// ---------------- row scale from partial sumsq ----------------
__global__ void rowscale_kernel(const float* __restrict__ partials, float* __restrict__ scale,
                                int N, int nSlices) {
    int r = blockIdx.x * blockDim.x + threadIdx.x;
    if (r >= N) return;
    float s = 0.f;
    for (int k = 0; k < nSlices; ++k) s += partials[(size_t)k * N + r];
    float n = sqrtf(s);
    scale[r] = fminf(1.f, MAXN / fmaxf(n, EPSF));
}

// ---------------- 6-phase 32x32-MFMA split-bf16 GEMM, fragment prefetch-ahead ----------------
// C[N x M] = (sA_r * A) @ W^T + bias. A planes [N][K], W planes [M][K].
// BM = IM*32 (256 or 128), BN = 256, BK = 32. 8 waves 2(M) x 4(N); wave owns (IM*16) x 64.
// 3-term split (hi*hi + hi*lo + lo*hi) as 6 phases x MT*2 MFMA (32x32x16).
// Phase p issues ds_reads for phase p+1 before its MFMA cluster -> read latency hides.
// Staging of next tile spread over Ph0-Ph3; single vmcnt(0) at tile end.
// LDS slot permutation: phys = swap(s_l) ^ ((row>>1)&3), swap = bit0<->bit1 (see fragld).
template<int OUTMODE, int IM>
__global__ __launch_bounds__(512, 2) void gemm_v6(
    const ushortT* __restrict__ Ah_g, const ushortT* __restrict__ Al_g,
    const ushortT* __restrict__ Wh_g, const ushortT* __restrict__ Wl_g,
    const float* __restrict__ bias, const float* __restrict__ scaleA,
    float* __restrict__ outF, ushortT* __restrict__ outH, ushortT* __restrict__ outL,
    float* __restrict__ partials, int K, int M, int nColBlk, int Nrows)
{
    constexpr int BM = IM * 32;
    constexpr int MT = IM / 2;          // 32-row M tiles per wave
    constexpr int AS = BM * 32;         // per-plane A elems per buffer
    constexpr int BS = 256 * 32;        // per-plane B elems
    constexpr int BUF = 2 * AS + 2 * BS;
    __shared__ __align__(16) ushortT lds[2 * BUF];

    const int tid = threadIdx.x;
    const int wid = tid >> 6, lane = tid & 63;
    const int nwg = gridDim.x;
    const int swz = ((int)blockIdx.x & 7) * (nwg >> 3) + ((int)blockIdx.x >> 3);
    const int rb = swz / nColBlk, cb = swz % nColBlk;
    const int rowBase = rb * BM, colBase = cb * 256;

    // staging: one round = 512 thr x 16B = 128 rows x 32 elems, LDS dest linear.
    // source logical slot for phys p at row rl: s = swap(p ^ x(rl))
    const int rl = tid >> 2;
    const int vsl = (tid & 3) ^ ((rl >> 1) & 3);
    const int ks = ((vsl & 1) << 1) | (vsl >> 1);
    const int d8 = tid * 8;
    const ushortT* gAh0 = Ah_g + (size_t)(rowBase + rl) * K + ks * 8;
    const ushortT* gAl0 = Al_g + (size_t)(rowBase + rl) * K + ks * 8;
    const ushortT* gAh1 = Ah_g + (size_t)(rowBase + 128 + rl) * K + ks * 8;  // IM==8 only
    const ushortT* gAl1 = Al_g + (size_t)(rowBase + 128 + rl) * K + ks * 8;
    const ushortT* gBh0 = Wh_g + (size_t)(colBase + rl) * K + ks * 8;
    const ushortT* gBh1 = Wh_g + (size_t)(colBase + 128 + rl) * K + ks * 8;
    const ushortT* gBl0 = Wl_g + (size_t)(colBase + rl) * K + ks * 8;
    const ushortT* gBl1 = Wl_g + (size_t)(colBase + 128 + rl) * K + ks * 8;
#define STG(p, dst, nbo, nk) gload_lds16((p) + (nk), &lds[(nbo) + (dst) + d8])

    // fragment addressing (32x32x16: row/col = lane&31, k-group = lane>>5)
    const int warpM = wid >> 2, warpN = wid & 3;     // 2 x 4
    const int l31 = lane & 31, lh = lane >> 5;
    const int arow0 = warpM * (IM * 16) + l31;
    const int brow0 = warpN * 64 + l31;

    f32_16 acc[MT][2];
#pragma unroll
    for (int m = 0; m < MT; ++m)
#pragma unroll
        for (int n = 0; n < 2; ++n)
#pragma unroll
            for (int r = 0; r < 16; ++r) acc[m][n][r] = 0.f;

    // prologue: stage tile 0 into buffer 0
    STG(gAh0, 0, 0, 0);
    if constexpr (IM == 8) STG(gAh1, 4096, 0, 0);
    STG(gAl0, AS, 0, 0);
    if constexpr (IM == 8) STG(gAl1, AS + 4096, 0, 0);
    STG(gBh0, 2 * AS, 0, 0); STG(gBh1, 2 * AS + 4096, 0, 0);
    STG(gBl0, 2 * AS + BS, 0, 0); STG(gBl1, 2 * AS + BS + 4096, 0, 0);
    asm volatile("s_waitcnt vmcnt(0)" ::: "memory");
    BAR;

    const int nt = K >> 5;
    for (int t = 0; t < nt; ++t) {
        const ushortT* lb = &lds[(t & 1) * BUF];
        const int nbo = ((t & 1) ^ 1) * BUF;
        const int nk = (t + 1) << 5;
        const bool more = (t + 1) < nt;
        const ushortT* lAh = lb;
        const ushortT* lAl = lb + AS;
        const ushortT* lBh = lb + 2 * AS;
        const ushortT* lBl = lb + 2 * AS + BS;

        bf16_8 ah0[MT], ah1[MT], bh0[2], bh1[2], bl0[2], bl1[2], al0[MT], al1[MT];

        // ---- Ph0 own reads + stage Ah ----
#pragma unroll
        for (int m = 0; m < MT; ++m) ah0[m] = fragld(lAh, arow0 + m * 32, 0, lh);
        bh0[0] = fragld(lBh, brow0, 0, lh);
        bh0[1] = fragld(lBh, brow0 + 32, 0, lh);
        if (more) {
            STG(gAh0, 0, nbo, nk);
            if constexpr (IM == 8) STG(gAh1, 4096, nbo, nk);
        }
        BAR;
        // ---- Ph0 MFMA (hi*hi k0) + Ph1 reads ----
#pragma unroll
        for (int m = 0; m < MT; ++m) ah1[m] = fragld(lAh, arow0 + m * 32, 1, lh);
        bh1[0] = fragld(lBh, brow0, 1, lh);
        bh1[1] = fragld(lBh, brow0 + 32, 1, lh);
        __builtin_amdgcn_s_setprio(1);
#pragma unroll
        for (int m = 0; m < MT; ++m) {
            acc[m][0] = MFMA32(ah0[m], bh0[0], acc[m][0], 0, 0, 0);
            acc[m][1] = MFMA32(ah0[m], bh0[1], acc[m][1], 0, 0, 0);
        }
        __builtin_amdgcn_s_setprio(0);
        BAR;
        // ---- Ph1 MFMA (hi*hi k1) + Ph2 reads + stage Al ----
        bl0[0] = fragld(lBl, brow0, 0, lh);
        bl0[1] = fragld(lBl, brow0 + 32, 0, lh);
        if (more) {
            STG(gAl0, AS, nbo, nk);
            if constexpr (IM == 8) STG(gAl1, AS + 4096, nbo, nk);
        }
        __builtin_amdgcn_s_setprio(1);
#pragma unroll
        for (int m = 0; m < MT; ++m) {
            acc[m][0] = MFMA32(ah1[m], bh1[0], acc[m][0], 0, 0, 0);
            acc[m][1] = MFMA32(ah1[m], bh1[1], acc[m][1], 0, 0, 0);
        }
        __builtin_amdgcn_s_setprio(0);
        BAR;
        // ---- Ph2 MFMA (hi*lo k0) + Ph3 reads + stage Bh ----
        bl1[0] = fragld(lBl, brow0, 1, lh);
        bl1[1] = fragld(lBl, brow0 + 32, 1, lh);
        if (more) { STG(gBh0, 2 * AS, nbo, nk); STG(gBh1, 2 * AS + 4096, nbo, nk); }
        __builtin_amdgcn_s_setprio(1);
#pragma unroll
        for (int m = 0; m < MT; ++m) {
            acc[m][0] = MFMA32(ah0[m], bl0[0], acc[m][0], 0, 0, 0);
            acc[m][1] = MFMA32(ah0[m], bl0[1], acc[m][1], 0, 0, 0);
        }
        __builtin_amdgcn_s_setprio(0);
        BAR;
        // ---- Ph3 MFMA (hi*lo k1) + Ph4 reads + stage Bl ----
#pragma unroll
        for (int m = 0; m < MT; ++m) al0[m] = fragld(lAl, arow0 + m * 32, 0, lh);
        if (more) { STG(gBl0, 2 * AS + BS, nbo, nk); STG(gBl1, 2 * AS + BS + 4096, nbo, nk); }
        __builtin_amdgcn_s_setprio(1);
#pragma unroll
        for (int m = 0; m < MT; ++m) {
            acc[m][0] = MFMA32(ah1[m], bl1[0], acc[m][0], 0, 0, 0);
            acc[m][1] = MFMA32(ah1[m], bl1[1], acc[m][1], 0, 0, 0);
        }
        __builtin_amdgcn_s_setprio(0);
        BAR;
        // ---- Ph4 MFMA (lo*hi k0) + Ph5 reads ----
#pragma unroll
        for (int m = 0; m < MT; ++m) al1[m] = fragld(lAl, arow0 + m * 32, 1, lh);
        __builtin_amdgcn_s_setprio(1);
#pragma unroll
        for (int m = 0; m < MT; ++m) {
            acc[m][0] = MFMA32(al0[m], bh0[0], acc[m][0], 0, 0, 0);
            acc[m][1] = MFMA32(al0[m], bh0[1], acc[m][1], 0, 0, 0);
        }
        __builtin_amdgcn_s_setprio(0);
        BAR;
        // ---- Ph5 MFMA (lo*hi k1) ----
        __builtin_amdgcn_s_setprio(1);
#pragma unroll
        for (int m = 0; m < MT; ++m) {
            acc[m][0] = MFMA32(al1[m], bh1[0], acc[m][0], 0, 0, 0);
            acc[m][1] = MFMA32(al1[m], bh1[1], acc[m][1], 0, 0, 0);
        }
        __builtin_amdgcn_s_setprio(0);
        asm volatile("s_waitcnt vmcnt(0)" ::: "memory");
        BAR;
    }
#undef STG

    // ---------------- epilogue (C/D: col=lane&31, row=(r&3)+8*(r>>2)+4*lh) ----------------
    const int cbase = colBase + warpN * 64 + l31;
    float bv[2] = {bias[cbase], bias[cbase + 32]};
    if (OUTMODE == 0) {
        const size_t slice = (size_t)(cb * 4 + warpN) * Nrows;
#pragma unroll
        for (int m = 0; m < MT; ++m) {
            const int rbase = rowBase + warpM * (IM * 16) + m * 32 + 4 * lh;
#pragma unroll
            for (int q = 0; q < 4; ++q) {
                float4 sa4 = float4{1.f, 1.f, 1.f, 1.f};
                if (scaleA) sa4 = *reinterpret_cast<const float4*>(&scaleA[rbase + q * 8]);
#pragma unroll
                for (int rr = 0; rr < 4; ++rr) {
                    const int r = q * 4 + rr;
                    const int row = rbase + q * 8 + rr;
                    const float sa = reinterpret_cast<const float*>(&sa4)[rr];
                    float y0 = sa * acc[m][0][r] + bv[0];
                    if (cbase == 0) y0 = 0.f;              // tangent component 0
                    float y1 = sa * acc[m][1][r] + bv[1];
                    ushortT h0, l0, h1, l1;
                    bsplit(y0, h0, l0); bsplit(y1, h1, l1);
                    const size_t base = (size_t)row * M;
                    outH[base + cbase] = h0; outH[base + cbase + 32] = h1;
                    outL[base + cbase] = l0; outL[base + cbase + 32] = l1;
                    float ssv = y0 * y0 + y1 * y1;
                    ssv += __shfl_xor(ssv, 1, 64); ssv += __shfl_xor(ssv, 2, 64);
                    ssv += __shfl_xor(ssv, 4, 64); ssv += __shfl_xor(ssv, 8, 64);
                    ssv += __shfl_xor(ssv, 16, 64);
                    if (l31 == 0) partials[slice + row] = ssv;
                }
            }
        }
    } else {
#pragma unroll
        for (int m = 0; m < MT; ++m) {
            const int rbase = rowBase + warpM * (IM * 16) + m * 32 + 4 * lh;
#pragma unroll
            for (int q = 0; q < 4; ++q) {
                float4 sa4 = float4{1.f, 1.f, 1.f, 1.f};
                if (scaleA) sa4 = *reinterpret_cast<const float4*>(&scaleA[rbase + q * 8]);
#pragma unroll
                for (int rr = 0; rr < 4; ++rr) {
                    const int r = q * 4 + rr;
                    const int row = rbase + q * 8 + rr;
                    const float sa = reinterpret_cast<const float*>(&sa4)[rr];
                    const size_t base = (size_t)row * M;
                    outF[base + cbase]      = sa * acc[m][0][r] + bv[0];
                    outF[base + cbase + 32] = sa * acc[m][1][r] + bv[1];
                }
            }
        }
    }
}

// ---------------- final Lorentz chain, rows of 256 ----------------
__global__ void final_kernel(const float* __restrict__ y2buf, const float* __restrict__ z,
                             const float* __restrict__ alpha_p, const float* __restrict__ step_p,
                             float* __restrict__ out, int N) {
    int gw = (blockIdx.x * blockDim.x + threadIdx.x) >> 6;
    int lane = threadIdx.x & 63;
    if (gw >= N) return;
    const bool l0 = (lane == 0);

    float4 yv = reinterpret_cast<const float4*>(y2buf + (size_t)gw * 256)[lane];
    float4 zv = reinterpret_cast<const float4*>(z + (size_t)gw * 256)[lane];
    float z0 = __shfl(zv.x, 0, 64);

    float yx = l0 ? 0.f : yv.x;
    float ss2 = wred(yx * yx + yv.y * yv.y + yv.z * yv.z + yv.w * yv.w);
    float n2 = sqrtf(ss2);
    float s2 = fminf(1.f, MAXN / fmaxf(n2, EPSF));
    float step = 1.f / (1.f + expf(-step_p[0]));
    float k1 = s2 * step;
    float vfx = yx * k1, vfy = yv.y * k1, vfz = yv.z * k1, vfw = yv.w * k1;

    float r2 = wred(vfx * vfx + vfy * vfy + vfz * vfz + vfw * vfw);
    float n = sqrtf(fmaxf(r2, 0.f));
    float sc = fminf(1.f, MAXN / fmaxf(n, EPSF));
    float m = fminf(n, MAXN);
    float ch = coshf(m), sd = sinh_div_f(m);
    float ex = ch * zv.x + sd * sc * vfx;
    float ey = ch * zv.y + sd * sc * vfy;
    float ez = ch * zv.z + sd * sc * vfz;
    float ew = ch * zv.w + sd * sc * vfw;
    float exq = l0 ? 0.f : ex;
    float r3 = wred(exq * exq + ey * ey + ez * ez + ew * ew);
    float u0 = sqrtf(1.f + r3);

    float r4 = wred((l0 ? 0.f : zv.x * ex) + zv.y * ey + zv.z * ez + zv.w * ew);
    float ip = r4 - z0 * u0;
    ip = fminf(ip, -(1.f + EPSF));
    float dd = acoshf(-ip);
    float g = div_sinh_f(dd);
    float a = 1.f / (1.f + expf(-alpha_p[0]));
    float oa = (1.f - a) * g;
    float st0 = oa * (u0 + ip * z0);
    float stx = oa * (ex + ip * zv.x);
    float sty = oa * (ey + ip * zv.y);
    float stz = oa * (ez + ip * zv.z);
    float stw = oa * (ew + ip * zv.w);
    float stxq = l0 ? 0.f : stx;

    float r5 = wred(stxq * stxq + sty * sty + stz * stz + stw * stw);
    float vv2 = r5 - st0 * st0;
    float n5 = sqrtf(fmaxf(vv2, 0.f));
    float s5 = fminf(1.f, MAXN / fmaxf(n5, EPSF));
    float m5 = fminf(n5, MAXN);
    float ch5 = coshf(m5), sd5 = sinh_div_f(m5);
    float fx = ch5 * zv.x + sd5 * s5 * stxq;
    float fy = ch5 * zv.y + sd5 * s5 * sty;
    float fz = ch5 * zv.z + sd5 * s5 * stz;
    float fw = ch5 * zv.w + sd5 * s5 * stw;
    float fxq = l0 ? 0.f : fx;
    float r6 = wred(fxq * fxq + fy * fy + fz * fz + fw * fw);
    float zn0 = sqrtf(1.f + r6);
    if (l0) fx = zn0;

    float4 o;
    o.x = fx; o.y = fy; o.z = fz; o.w = fw;
    reinterpret_cast<float4*>(out + (size_t)gw * 256)[lane] = o;
    reinterpret_cast<float4*>(out + ((size_t)N + gw) * 256)[lane] = zv;
}

extern "C" void kernel_launch(void* const* d_in, const int* in_sizes, int n_in,
                              void* d_out, int out_size, void* d_ws, size_t ws_size,
                              hipStream_t stream) {
    const float* z_h  = (const float*)d_in[0];
    const float* w0   = (const float*)d_in[1];
    const float* b0   = (const float*)d_in[2];
    const float* w1   = (const float*)d_in[3];
    const float* b1   = (const float*)d_in[4];
    const float* w2   = (const float*)d_in[5];
    const float* b2   = (const float*)d_in[6];
    const float* alph = (const float*)d_in[7];
    const float* stps = (const float*)d_in[8];
    float* out = (float*)d_out;

    const int D = 256, H = 1024;
    const int N = in_sizes[0] / D;   // 32768

    // ---- d_out head arena (all dead before final_kernel writes out) ----
    char* arena = (char*)d_out;
    ushortT* w0h = (ushortT*)(arena + 0);              // 512 KB
    ushortT* w0l = (ushortT*)(arena + 524288);
    ushortT* w1h = (ushortT*)(arena + 1048576);        // 2 MB
    ushortT* w1l = (ushortT*)(arena + 3145728);
    ushortT* w2h = (ushortT*)(arena + 5242880);        // 512 KB
    ushortT* w2l = (ushortT*)(arena + 5767168);
    float* partials = (float*)(arena + 6291456);       // 16 * N * 4 = 2 MB
    float* s1 = (float*)(arena + 10485760);            // N * 4
    float* s2 = (float*)(arena + 10616832);            // N * 4
    ushortT* p0h = (ushortT*)(arena + 10747904);       // N*256*2 = 16 MB
    ushortT* p0l = (ushortT*)(arena + 27525120);       // ends 42.25 MB < 64 MB

    // ---- workspace: two N x 1024 plane pairs (exactly 256 MB) ----
    ushortT* paH = (ushortT*)d_ws;
    ushortT* paL = paH + (size_t)N * H;
    ushortT* pbH = paL + (size_t)N * H;
    ushortT* pbL = pbH + (size_t)N * H;
    float* y2F = (float*)d_ws;   // 32 MB, reuses paH head (dead after GEMM1)

    split_kernel<<<(H * D / 4 + 255) / 256, 256, 0, stream>>>(w0, w0h, w0l, H * D / 4);
    split_kernel<<<(H * H / 4 + 255) / 256, 256, 0, stream>>>(w1, w1h, w1l, H * H / 4);
    split_kernel<<<(D * H / 4 + 255) / 256, 256, 0, stream>>>(w2, w2h, w2l, D * H / 4);

    prep_kernel<<<N / 4, 256, 0, stream>>>(z_h, p0h, p0l, N);

    // GEMM0: y0 = prepPlanes @ W0^T + b0 -> planes paH/paL + partials (16 slices)
    gemm_v6<0, 8><<<(N / 256) * (H / 256), 512, 0, stream>>>(
        p0h, p0l, w0h, w0l, b0, nullptr, nullptr, paH, paL, partials, D, H, H / 256, N);
    rowscale_kernel<<<(N + 255) / 256, 256, 0, stream>>>(partials, s1, N, 16);

    // GEMM1: y1 = (s1 * y0planes) @ W1^T + b1 -> planes pbH/pbL + partials
    gemm_v6<0, 8><<<(N / 256) * (H / 256), 512, 0, stream>>>(
        paH, paL, w1h, w1l, b1, s1, nullptr, pbH, pbL, partials, H, H, H / 256, N);
    rowscale_kernel<<<(N + 255) / 256, 256, 0, stream>>>(partials, s2, N, 16);

    // GEMM2: y2 = (s2 * y1planes) @ W2^T + b2 -> f32 (BM=128 for full CU coverage)
    gemm_v6<1, 4><<<(N / 128) * (D / 256), 512, 0, stream>>>(
        pbH, pbL, w2h, w2l, b2, s2, y2F, nullptr, nullptr, nullptr, H, D, D / 256, N);

    final_kernel<<<N / 4, 256, 0, stream>>>(y2F, z_h, alph, stps, out, N);
}

// Round 7
// 391.123 us; speedup vs baseline: 1.0978x; 1.0978x over previous
//
#include <hip/hip_runtime.h>
#include <math.h>

#define EPSF 1e-7f
#define MAXN 10.0f

typedef unsigned short ushortT;
typedef __bf16 bf16_8 __attribute__((ext_vector_type(8)));
typedef float f32_4 __attribute__((ext_vector_type(4)));

#define MFMA16 __builtin_amdgcn_mfma_f32_16x16x32_bf16
#define BAR asm volatile("s_barrier" ::: "memory")

__device__ __forceinline__ float sinh_div_f(float d) {
    float ds = fmaxf(d, 1e-6f);
    return (d < 1e-6f) ? 1.0f : sinhf(ds) / ds;
}
__device__ __forceinline__ float div_sinh_f(float d) {
    float ds = fmaxf(d, 1e-6f);
    return (d < 1e-6f) ? 1.0f : ds / sinhf(ds);
}
__device__ __forceinline__ float wred(float v) {
#pragma unroll
    for (int off = 32; off > 0; off >>= 1) v += __shfl_xor(v, off, 64);
    return v;
}
__device__ __forceinline__ float red16(float v) {   // sum across frow (lane bits 0-3)
    v += __shfl_xor(v, 1, 64); v += __shfl_xor(v, 2, 64);
    v += __shfl_xor(v, 4, 64); v += __shfl_xor(v, 8, 64);
    return v;
}
// f32 -> bf16(hi) + bf16(lo), both RNE
__device__ __forceinline__ void bsplit(float x, ushortT& h, ushortT& l) {
    unsigned u = __float_as_uint(x);
    unsigned r = (u + 0x7fffu + ((u >> 16) & 1u)) >> 16;
    h = (ushortT)r;
    float lo = x - __uint_as_float(r << 16);
    unsigned ul = __float_as_uint(lo);
    l = (ushortT)((ul + 0x7fffu + ((ul >> 16) & 1u)) >> 16);
}
__device__ __forceinline__ void gload_lds16(const void* g, void* l) {
    __builtin_amdgcn_global_load_lds(
        (const __attribute__((address_space(1))) unsigned int*)g,
        (__attribute__((address_space(3))) unsigned int*)l, 16, 0, 0);
}
__device__ __forceinline__ void split_item(const float* __restrict__ x,
                                           ushortT* __restrict__ hi, ushortT* __restrict__ lo,
                                           int idx) {
    float4 v = reinterpret_cast<const float4*>(x)[idx];
    float f[4] = {v.x, v.y, v.z, v.w};
    ushortT hh[4], ll[4];
#pragma unroll
    for (int e = 0; e < 4; ++e) bsplit(f[e], hh[e], ll[e]);
    reinterpret_cast<ushort4*>(hi)[idx] = ushort4{hh[0], hh[1], hh[2], hh[3]};
    reinterpret_cast<ushort4*>(lo)[idx] = ushort4{ll[0], ll[1], ll[2], ll[3]};
}

// ---------------- combo1: split w0, split w1, prep(z -> p0 planes) ----------------
__global__ void combo1(const float* __restrict__ z, const float* __restrict__ w0,
                       const float* __restrict__ w1,
                       ushortT* __restrict__ p0h, ushortT* __restrict__ p0l,
                       ushortT* __restrict__ w0h, ushortT* __restrict__ w0l,
                       ushortT* __restrict__ w1h, ushortT* __restrict__ w1l, int N) {
    int b = blockIdx.x, tid = threadIdx.x;
    if (b < 256) {                       // w0: 65536 float4 items
        split_item(w0, w0h, w0l, b * 256 + tid);
        return;
    }
    if (b < 1280) {                      // w1: 262144 items
        split_item(w1, w1h, w1l, (b - 256) * 256 + tid);
        return;
    }
    // prep: one wave per 256-row
    int gw = (b - 1280) * 4 + (tid >> 6);
    int lane = tid & 63;
    if (gw >= N) return;
    float4 zv = reinterpret_cast<const float4*>(z + (size_t)gw * 256)[lane];
    float z0 = __shfl(zv.x, 0, 64);
    float x0 = fmaxf(z0, 1.f + EPSF);
    float d = acoshf(x0);
    float f = div_sinh_f(d);
    float vx = (lane == 0) ? 0.f : zv.x * f;
    float vy = zv.y * f, vz = zv.z * f, vw = zv.w * f;
    float ss = wred(vx * vx + vy * vy + vz * vz + vw * vw);
    float n = sqrtf(ss);
    float s = fminf(1.f, MAXN / fmaxf(n, EPSF));
    float o[4] = {vx * s, vy * s, vz * s, vw * s};
    ushortT hh[4], ll[4];
#pragma unroll
    for (int e = 0; e < 4; ++e) bsplit(o[e], hh[e], ll[e]);
    reinterpret_cast<ushort4*>(p0h + (size_t)gw * 256)[lane] = ushort4{hh[0], hh[1], hh[2], hh[3]};
    reinterpret_cast<ushort4*>(p0l + (size_t)gw * 256)[lane] = ushort4{ll[0], ll[1], ll[2], ll[3]};
}

// ---------------- rowscale (standalone, for s1) ----------------
__global__ void rowscale_kernel(const float* __restrict__ partials, float* __restrict__ scale,
                                int N, int nSlices) {
    int r = blockIdx.x * blockDim.x + threadIdx.x;
    if (r >= N) return;
    float s = 0.f;
    for (int k = 0; k < nSlices; ++k) s += partials[(size_t)k * N + r];
    float n = sqrtf(s);
    scale[r] = fminf(1.f, MAXN / fmaxf(n, EPSF));
}

// ---------------- combo2: rowscale(s2) + split w2 ----------------
__global__ void combo2(const float* __restrict__ partials, float* __restrict__ s2,
                       const float* __restrict__ w2,
                       ushortT* __restrict__ w2h, ushortT* __restrict__ w2l, int N) {
    int b = blockIdx.x, tid = threadIdx.x;
    if (b < 128) {
        int r = b * 256 + tid;
        if (r >= N) return;
        float s = 0.f;
        for (int k = 0; k < 16; ++k) s += partials[(size_t)k * N + r];
        float n = sqrtf(s);
        s2[r] = fminf(1.f, MAXN / fmaxf(n, EPSF));
        return;
    }
    split_item(w2, w2h, w2l, (b - 128) * 256 + tid);
}

// ---------------- 6-phase 16x16-MFMA split-bf16 GEMM (v4 geometry, counted vmcnt) ----------
// C[N x M] = (sA_r * A) @ W^T + bias. BM = IM*32, BN = 256, BK = 32. 8 waves 2(M) x 4(N).
// OUTMODE 0: bf16 hi/lo planes + partial row-sumsq. OUTMODE 2: fused Lorentz-final epilogue
// (requires colBase==0, M==256, IM==4; writes both output slots of `out`).
template<int OUTMODE, int IM>
__global__ __launch_bounds__(512, 2) void gemm_v7(
    const ushortT* __restrict__ Ah_g, const ushortT* __restrict__ Al_g,
    const ushortT* __restrict__ Wh_g, const ushortT* __restrict__ Wl_g,
    const float* __restrict__ bias, const float* __restrict__ scaleA,
    float* __restrict__ outF, ushortT* __restrict__ outH, ushortT* __restrict__ outL,
    float* __restrict__ partials, int K, int M, int nColBlk, int Nrows,
    const float* __restrict__ z_g, const float* __restrict__ alpha_p,
    const float* __restrict__ step_p)
{
    constexpr int BM = IM * 32;
    constexpr int AS = BM * 32;
    constexpr int BS = 256 * 32;
    constexpr int BUF = 2 * AS + 2 * BS;
    constexpr int HM = IM / 2;
    __shared__ __align__(16) ushortT lds[2 * BUF];

    const int tid = threadIdx.x;
    const int wid = tid >> 6, lane = tid & 63;
    const int nwg = gridDim.x;
    const int swz = ((int)blockIdx.x & 7) * (nwg >> 3) + ((int)blockIdx.x >> 3);
    const int rb = swz / nColBlk, cb = swz % nColBlk;
    const int rowBase = rb * BM, colBase = cb * 256;

    const int rl = tid >> 2;
    const int ks = (tid & 3) ^ ((rl >> 1) & 3);
    const int d8 = tid * 8;
    const ushortT* gAh0 = Ah_g + (size_t)(rowBase + rl) * K + ks * 8;
    const ushortT* gAl0 = Al_g + (size_t)(rowBase + rl) * K + ks * 8;
    const ushortT* gAh1 = Ah_g + (size_t)(rowBase + 128 + rl) * K + ks * 8;  // IM==8 only
    const ushortT* gAl1 = Al_g + (size_t)(rowBase + 128 + rl) * K + ks * 8;
    const ushortT* gBh0 = Wh_g + (size_t)(colBase + rl) * K + ks * 8;
    const ushortT* gBh1 = Wh_g + (size_t)(colBase + 128 + rl) * K + ks * 8;
    const ushortT* gBl0 = Wl_g + (size_t)(colBase + rl) * K + ks * 8;
    const ushortT* gBl1 = Wl_g + (size_t)(colBase + 128 + rl) * K + ks * 8;
#define STG(p, dst, nbo, nk) gload_lds16((p) + (nk), &lds[(nbo) + (dst) + d8])

    const int warpM = wid >> 2, warpN = wid & 3;
    const int frow = lane & 15, fk = lane >> 4;
    const int pslot8 = (fk ^ ((frow >> 1) & 3)) * 8;
    const int aoff = (warpM * (IM * 16) + frow) * 32 + pslot8;
    const int boff = (warpN * 64 + frow) * 32 + pslot8;

    f32_4 acc[IM][4];
#pragma unroll
    for (int i = 0; i < IM; ++i)
#pragma unroll
        for (int j = 0; j < 4; ++j) acc[i][j] = f32_4{0.f, 0.f, 0.f, 0.f};

    // prologue: stage tile 0 into buffer 0
    STG(gAh0, 0, 0, 0);
    if constexpr (IM == 8) STG(gAh1, 4096, 0, 0);
    STG(gAl0, AS, 0, 0);
    if constexpr (IM == 8) STG(gAl1, AS + 4096, 0, 0);
    STG(gBh0, 2 * AS, 0, 0); STG(gBh1, 2 * AS + 4096, 0, 0);
    STG(gBl0, 2 * AS + BS, 0, 0); STG(gBl1, 2 * AS + BS + 4096, 0, 0);
    asm volatile("s_waitcnt vmcnt(0)" ::: "memory");
    BAR;

    const int nt = K >> 5;
    for (int t = 0; t < nt; ++t) {
        const ushortT* lb = &lds[(t & 1) * BUF];
        const int nbo = ((t & 1) ^ 1) * BUF;
        const int nk = (t + 1) << 5;
        const bool more = (t + 1) < nt;
        bf16_8 ah[IM], bh[4], bl[4], alx[HM];

        // ---- P0: read ah[0..HM-1], bh[0..3]; stage Ah ----
#pragma unroll
        for (int i = 0; i < HM; ++i) ah[i] = *reinterpret_cast<const bf16_8*>(&lb[aoff + i * 512]);
#pragma unroll
        for (int j = 0; j < 4; ++j) bh[j] = *reinterpret_cast<const bf16_8*>(&lb[2 * AS + boff + j * 512]);
        if (more) { STG(gAh0, 0, nbo, nk); if constexpr (IM == 8) STG(gAh1, 4096, nbo, nk); }
        BAR;
        __builtin_amdgcn_s_setprio(1);
#pragma unroll
        for (int i = 0; i < HM; ++i)
#pragma unroll
            for (int j = 0; j < 4; ++j) acc[i][j] = MFMA16(ah[i], bh[j], acc[i][j], 0, 0, 0);
        __builtin_amdgcn_s_setprio(0);

        // ---- P1: read ah[HM..IM-1]; stage Al; counted wait drains Bl(t) ----
#pragma unroll
        for (int i = HM; i < IM; ++i) ah[i] = *reinterpret_cast<const bf16_8*>(&lb[aoff + i * 512]);
        if (more) {
            STG(gAl0, AS, nbo, nk);
            if constexpr (IM == 8) STG(gAl1, AS + 4096, nbo, nk);
            if constexpr (IM == 8) asm volatile("s_waitcnt vmcnt(4)" ::: "memory");
            else                   asm volatile("s_waitcnt vmcnt(2)" ::: "memory");
        } else {
            asm volatile("s_waitcnt vmcnt(0)" ::: "memory");
        }
        BAR;
        __builtin_amdgcn_s_setprio(1);
#pragma unroll
        for (int i = HM; i < IM; ++i)
#pragma unroll
            for (int j = 0; j < 4; ++j) acc[i][j] = MFMA16(ah[i], bh[j], acc[i][j], 0, 0, 0);
        __builtin_amdgcn_s_setprio(0);

        // ---- P2: read bl[0..3]; stage Bh ----
#pragma unroll
        for (int j = 0; j < 4; ++j) bl[j] = *reinterpret_cast<const bf16_8*>(&lb[2 * AS + BS + boff + j * 512]);
        if (more) { STG(gBh0, 2 * AS, nbo, nk); STG(gBh1, 2 * AS + 4096, nbo, nk); }
        BAR;
        __builtin_amdgcn_s_setprio(1);
#pragma unroll
        for (int i = 0; i < HM; ++i)
#pragma unroll
            for (int j = 0; j < 4; ++j) acc[i][j] = MFMA16(ah[i], bl[j], acc[i][j], 0, 0, 0);
        __builtin_amdgcn_s_setprio(0);

        // ---- P3: stage Bl ----
        if (more) { STG(gBl0, 2 * AS + BS, nbo, nk); STG(gBl1, 2 * AS + BS + 4096, nbo, nk); }
        BAR;
        __builtin_amdgcn_s_setprio(1);
#pragma unroll
        for (int i = HM; i < IM; ++i)
#pragma unroll
            for (int j = 0; j < 4; ++j) acc[i][j] = MFMA16(ah[i], bl[j], acc[i][j], 0, 0, 0);
        __builtin_amdgcn_s_setprio(0);

        // ---- P4: read al (h=0) ----
#pragma unroll
        for (int i = 0; i < HM; ++i) alx[i] = *reinterpret_cast<const bf16_8*>(&lb[AS + aoff + i * 512]);
        BAR;
        __builtin_amdgcn_s_setprio(1);
#pragma unroll
        for (int i = 0; i < HM; ++i)
#pragma unroll
            for (int j = 0; j < 4; ++j) acc[i][j] = MFMA16(alx[i], bh[j], acc[i][j], 0, 0, 0);
        __builtin_amdgcn_s_setprio(0);

        // ---- P5: read al (h=1) ----
#pragma unroll
        for (int i = 0; i < HM; ++i) alx[i] = *reinterpret_cast<const bf16_8*>(&lb[AS + aoff + (HM + i) * 512]);
        BAR;
        __builtin_amdgcn_s_setprio(1);
#pragma unroll
        for (int i = 0; i < HM; ++i)
#pragma unroll
            for (int j = 0; j < 4; ++j) acc[HM + i][j] = MFMA16(alx[i], bh[j], acc[HM + i][j], 0, 0, 0);
        __builtin_amdgcn_s_setprio(0);

        // ---- tail: counted drain (leave Bl(t+1) in flight; it is guarded at P1) ----
        asm volatile("s_waitcnt vmcnt(2)" ::: "memory");
        BAR;
    }
#undef STG

    // ---------------- epilogue ----------------
    const int cbase = colBase + warpN * 64 + frow;
    if constexpr (OUTMODE == 0) {
        float bv[4];
#pragma unroll
        for (int j = 0; j < 4; ++j) bv[j] = bias[cbase + j * 16];
        const size_t slice = (size_t)(cb * 4 + warpN) * Nrows;
#pragma unroll
        for (int i = 0; i < IM; ++i) {
            const int row0 = rowBase + warpM * (IM * 16) + i * 16 + fk * 4;
            float4 sa4 = float4{1.f, 1.f, 1.f, 1.f};
            if (scaleA) sa4 = *reinterpret_cast<const float4*>(&scaleA[row0]);
            float psum[4];
#pragma unroll
            for (int r = 0; r < 4; ++r) {
                const float sa = reinterpret_cast<const float*>(&sa4)[r];
                const int row = row0 + r;
                const size_t base = (size_t)row * M;
                float ssv = 0.f;
#pragma unroll
                for (int j = 0; j < 4; ++j) {
                    float y = sa * acc[i][j][r] + bv[j];
                    if (j == 0 && cbase == 0) y = 0.f;
                    ushortT h, l;
                    bsplit(y, h, l);
                    outH[base + cbase + j * 16] = h;
                    outL[base + cbase + j * 16] = l;
                    ssv += y * y;
                }
                psum[r] = red16(ssv);
            }
            if (frow == 0) {
#pragma unroll
                for (int r = 0; r < 4; ++r) partials[slice + row0 + r] = psum[r];
            }
        }
    }
    if constexpr (OUTMODE == 2) {
        // fused Lorentz-final chain. colBase==0, M==256, BM==128 (IM==4).
        float* red  = (float*)&lds[0];
        float* bufZ = red;              // [128]
        float* bufA = red + 128;        // [128][4]
        float* bufB = red + 640;        // [128][8]
        float* bufC = red + 1664;       // [128][4]
        float* bufD = red + 2176;       // [128][4]
        const float stepv = 1.f / (1.f + expf(-step_p[0]));
        const float av    = 1.f / (1.f + expf(-alpha_p[0]));
        const int cb0 = warpN * 64 + frow;
        const bool c0own = (cb0 == 0);
        float bv[4];
#pragma unroll
        for (int j = 0; j < 4; ++j) bv[j] = bias[cb0 + j * 16];
        BAR;
#pragma unroll
        for (int ig = 0; ig < 2; ++ig) {
            float yv[2][4][4], zz[2][4][4], z0[2][4], st0[2][4];
            // y = sA*acc + b ; load z
#pragma unroll
            for (int ii = 0; ii < 2; ++ii) {
                const int i = ig * 2 + ii;
                const int row0 = warpM * 64 + i * 16 + fk * 4;
                float4 sa4 = float4{1.f, 1.f, 1.f, 1.f};
                if (scaleA) sa4 = *reinterpret_cast<const float4*>(&scaleA[rowBase + row0]);
#pragma unroll
                for (int rr = 0; rr < 4; ++rr) {
                    const float sa = reinterpret_cast<const float*>(&sa4)[rr];
                    const size_t gz = (size_t)(rowBase + row0 + rr) * 256 + cb0;
#pragma unroll
                    for (int j = 0; j < 4; ++j) {
                        yv[ii][j][rr] = sa * acc[i][j][rr] + bv[j];
                        zz[ii][j][rr] = z_g[gz + j * 16];
                    }
                }
            }
            // R1: ssq of v_transformed (cols >= 1); publish z0
#pragma unroll
            for (int ii = 0; ii < 2; ++ii) {
                const int row0 = warpM * 64 + (ig * 2 + ii) * 16 + fk * 4;
#pragma unroll
                for (int rr = 0; rr < 4; ++rr) {
                    float p = 0.f;
#pragma unroll
                    for (int j = 0; j < 4; ++j) {
                        float yq = (c0own && j == 0) ? 0.f : yv[ii][j][rr];
                        p += yq * yq;
                    }
                    p = red16(p);
                    if (frow == 0) bufA[(row0 + rr) * 4 + warpN] = p;
                    if (c0own) bufZ[row0 + rr] = zz[ii][0][rr];
                }
            }
            BAR;
            // e = cosh(m)*z + sinh_div*sc*vf  (into yv); partials e^2, z*e
#pragma unroll
            for (int ii = 0; ii < 2; ++ii) {
                const int row0 = warpM * 64 + (ig * 2 + ii) * 16 + fk * 4;
#pragma unroll
                for (int rr = 0; rr < 4; ++rr) {
                    const int rw = row0 + rr;
                    float ss2 = bufA[rw * 4] + bufA[rw * 4 + 1] + bufA[rw * 4 + 2] + bufA[rw * 4 + 3];
                    z0[ii][rr] = bufZ[rw];
                    float n2 = sqrtf(ss2);
                    float k1 = fminf(1.f, MAXN / fmaxf(n2, EPSF)) * stepv;
                    float n  = k1 * n2;
                    float scv = fminf(1.f, MAXN / fmaxf(n, EPSF));
                    float m  = fminf(n, MAXN);
                    float ch = coshf(m), sdv = sinh_div_f(m);
                    float pe = 0.f, pz = 0.f;
#pragma unroll
                    for (int j = 0; j < 4; ++j) {
                        float vf = (c0own && j == 0) ? 0.f : yv[ii][j][rr] * k1;
                        float e  = ch * zz[ii][j][rr] + sdv * scv * vf;
                        yv[ii][j][rr] = e;
                        if (!(c0own && j == 0)) { pe += e * e; pz += zz[ii][j][rr] * e; }
                    }
                    pe = red16(pe); pz = red16(pz);
                    if (frow == 0) { bufB[rw * 8 + warpN * 2] = pe; bufB[rw * 8 + warpN * 2 + 1] = pz; }
                }
            }
            BAR;
            // logmap: st = oa*(e + ip*z) (into yv); partials st^2
#pragma unroll
            for (int ii = 0; ii < 2; ++ii) {
                const int row0 = warpM * 64 + (ig * 2 + ii) * 16 + fk * 4;
#pragma unroll
                for (int rr = 0; rr < 4; ++rr) {
                    const int rw = row0 + rr;
                    float r3 = bufB[rw * 8] + bufB[rw * 8 + 2] + bufB[rw * 8 + 4] + bufB[rw * 8 + 6];
                    float r4 = bufB[rw * 8 + 1] + bufB[rw * 8 + 3] + bufB[rw * 8 + 5] + bufB[rw * 8 + 7];
                    float u0 = sqrtf(1.f + r3);
                    float ip = fminf(r4 - z0[ii][rr] * u0, -(1.f + EPSF));
                    float dd = acoshf(-ip);
                    float g = div_sinh_f(dd);
                    float oa = (1.f - av) * g;
                    st0[ii][rr] = oa * (u0 + ip * z0[ii][rr]);
                    float p5 = 0.f;
#pragma unroll
                    for (int j = 0; j < 4; ++j) {
                        float st = oa * (yv[ii][j][rr] + ip * zz[ii][j][rr]);
                        yv[ii][j][rr] = st;
                        if (!(c0own && j == 0)) p5 += st * st;
                    }
                    p5 = red16(p5);
                    if (frow == 0) bufC[rw * 4 + warpN] = p5;
                }
            }
            BAR;
            // expmap: f = ch5*z + sd5*s5*st (into yv); partials f^2
#pragma unroll
            for (int ii = 0; ii < 2; ++ii) {
                const int row0 = warpM * 64 + (ig * 2 + ii) * 16 + fk * 4;
#pragma unroll
                for (int rr = 0; rr < 4; ++rr) {
                    const int rw = row0 + rr;
                    float r5 = bufC[rw * 4] + bufC[rw * 4 + 1] + bufC[rw * 4 + 2] + bufC[rw * 4 + 3];
                    float vv2 = r5 - st0[ii][rr] * st0[ii][rr];
                    float n5 = sqrtf(fmaxf(vv2, 0.f));
                    float s5 = fminf(1.f, MAXN / fmaxf(n5, EPSF));
                    float m5 = fminf(n5, MAXN);
                    float ch5 = coshf(m5), sd5 = sinh_div_f(m5);
                    float p6 = 0.f;
#pragma unroll
                    for (int j = 0; j < 4; ++j) {
                        float f = ch5 * zz[ii][j][rr] + sd5 * s5 * yv[ii][j][rr];
                        yv[ii][j][rr] = f;
                        if (!(c0own && j == 0)) p6 += f * f;
                    }
                    p6 = red16(p6);
                    if (frow == 0) bufD[rw * 4 + warpN] = p6;
                }
            }
            BAR;
            // projx + store z_next and z_h copy
#pragma unroll
            for (int ii = 0; ii < 2; ++ii) {
                const int row0 = warpM * 64 + (ig * 2 + ii) * 16 + fk * 4;
#pragma unroll
                for (int rr = 0; rr < 4; ++rr) {
                    const int rw = row0 + rr;
                    float r6 = bufD[rw * 4] + bufD[rw * 4 + 1] + bufD[rw * 4 + 2] + bufD[rw * 4 + 3];
                    float zn0 = sqrtf(1.f + r6);
                    const size_t rowG = (size_t)(rowBase + rw);
#pragma unroll
                    for (int j = 0; j < 4; ++j) {
                        const int col = cb0 + j * 16;
                        float v = (c0own && j == 0) ? zn0 : yv[ii][j][rr];
                        outF[rowG * 256 + col] = v;
                        outF[((size_t)Nrows + rowG) * 256 + col] = zz[ii][j][rr];
                    }
                }
            }
        }
    }
}

extern "C" void kernel_launch(void* const* d_in, const int* in_sizes, int n_in,
                              void* d_out, int out_size, void* d_ws, size_t ws_size,
                              hipStream_t stream) {
    const float* z_h  = (const float*)d_in[0];
    const float* w0   = (const float*)d_in[1];
    const float* b0   = (const float*)d_in[2];
    const float* w1   = (const float*)d_in[3];
    const float* b1   = (const float*)d_in[4];
    const float* w2   = (const float*)d_in[5];
    const float* b2   = (const float*)d_in[6];
    const float* alph = (const float*)d_in[7];
    const float* stps = (const float*)d_in[8];
    float* out = (float*)d_out;

    const int D = 256, H = 1024;
    const int N = in_sizes[0] / D;   // 32768

    // ---- d_out slot1 [0,32MB): p0 planes (dead after GEMM0; slot1 written by GEMM2 epi) ----
    char* ob = (char*)d_out;
    ushortT* p0h = (ushortT*)ob;                       // 16 MB
    ushortT* p0l = (ushortT*)(ob + 16777216);          // 16 MB
    // ---- d_out slot2 [32,64MB) scratch (all dead before GEMM2 epilogue writes the copy) ----
    char* s2b = ob + 33554432;
    ushortT* w0h = (ushortT*)(s2b);                    // 512 KB
    ushortT* w0l = (ushortT*)(s2b + 524288);
    ushortT* w1h = (ushortT*)(s2b + 1048576);          // 2 MB
    ushortT* w1l = (ushortT*)(s2b + 3145728);
    float* partials = (float*)(s2b + 5242880);         // 2 MB (16 x N)
    float* s1 = (float*)(s2b + 7340032);               // 128 KB  -> ends at ~39.5 MB

    // ---- d_ws: activation plane pairs; paH region reused for w2/s2 after GEMM1 ----
    ushortT* paH = (ushortT*)d_ws;                     // 64 MB
    ushortT* paL = paH + (size_t)N * H;                // 64 MB
    ushortT* pbH = paL + (size_t)N * H;                // 64 MB
    ushortT* pbL = pbH + (size_t)N * H;                // 64 MB
    ushortT* w2h = (ushortT*)d_ws;                     // 512 KB (written after GEMM1)
    ushortT* w2l = (ushortT*)((char*)d_ws + 524288);   // 512 KB
    float* s2 = (float*)((char*)d_ws + 1048576);       // 128 KB

    // split w0/w1 + prep
    combo1<<<1280 + N / 4, 256, 0, stream>>>(z_h, w0, w1, p0h, p0l, w0h, w0l, w1h, w1l, N);

    // GEMM0: y0 planes = prep @ W0^T + b0
    gemm_v7<0, 8><<<(N / 256) * (H / 256), 512, 0, stream>>>(
        p0h, p0l, w0h, w0l, b0, nullptr, nullptr, paH, paL, partials, D, H, H / 256, N,
        nullptr, nullptr, nullptr);
    rowscale_kernel<<<(N + 255) / 256, 256, 0, stream>>>(partials, s1, N, 16);

    // GEMM1: y1 planes = (s1*y0) @ W1^T + b1
    gemm_v7<0, 8><<<(N / 256) * (H / 256), 512, 0, stream>>>(
        paH, paL, w1h, w1l, b1, s1, nullptr, pbH, pbL, partials, H, H, H / 256, N,
        nullptr, nullptr, nullptr);

    // rowscale s2 + split w2 (into now-dead paH region)
    combo2<<<384, 256, 0, stream>>>(partials, s2, w2, w2h, w2l, N);

    // GEMM2 + fused Lorentz-final chain -> writes both output slots
    gemm_v7<2, 4><<<(N / 128) * (D / 256), 512, 0, stream>>>(
        pbH, pbL, w2h, w2l, b2, s2, out, nullptr, nullptr, nullptr, H, D, D / 256, N,
        z_h, alph, stps);
}

// Round 8
// 390.407 us; speedup vs baseline: 1.0998x; 1.0018x over previous
//
#include <hip/hip_runtime.h>
#include <math.h>

#define EPSF 1e-7f
#define MAXN 10.0f

typedef unsigned short ushortT;
typedef __bf16 bf16_8 __attribute__((ext_vector_type(8)));
typedef float f32_4 __attribute__((ext_vector_type(4)));

#define MFMA16 __builtin_amdgcn_mfma_f32_16x16x32_bf16
#define BAR asm volatile("s_barrier" ::: "memory")

__device__ __forceinline__ float sinh_div_f(float d) {
    float ds = fmaxf(d, 1e-6f);
    return (d < 1e-6f) ? 1.0f : sinhf(ds) / ds;
}
__device__ __forceinline__ float div_sinh_f(float d) {
    float ds = fmaxf(d, 1e-6f);
    return (d < 1e-6f) ? 1.0f : ds / sinhf(ds);
}
__device__ __forceinline__ float wred(float v) {
#pragma unroll
    for (int off = 32; off > 0; off >>= 1) v += __shfl_xor(v, off, 64);
    return v;
}
__device__ __forceinline__ float red16(float v) {   // sum across frow (lane bits 0-3)
    v += __shfl_xor(v, 1, 64); v += __shfl_xor(v, 2, 64);
    v += __shfl_xor(v, 4, 64); v += __shfl_xor(v, 8, 64);
    return v;
}
// f32 -> bf16(hi) + bf16(lo), both RNE
__device__ __forceinline__ void bsplit(float x, ushortT& h, ushortT& l) {
    unsigned u = __float_as_uint(x);
    unsigned r = (u + 0x7fffu + ((u >> 16) & 1u)) >> 16;
    h = (ushortT)r;
    float lo = x - __uint_as_float(r << 16);
    unsigned ul = __float_as_uint(lo);
    l = (ushortT)((ul + 0x7fffu + ((ul >> 16) & 1u)) >> 16);
}
__device__ __forceinline__ void gload_lds16(const void* g, void* l) {
    __builtin_amdgcn_global_load_lds(
        (const __attribute__((address_space(1))) unsigned int*)g,
        (__attribute__((address_space(3))) unsigned int*)l, 16, 0, 0);
}
__device__ __forceinline__ void split_item(const float* __restrict__ x,
                                           ushortT* __restrict__ hi, ushortT* __restrict__ lo,
                                           int idx) {
    float4 v = reinterpret_cast<const float4*>(x)[idx];
    float f[4] = {v.x, v.y, v.z, v.w};
    ushortT hh[4], ll[4];
#pragma unroll
    for (int e = 0; e < 4; ++e) bsplit(f[e], hh[e], ll[e]);
    reinterpret_cast<ushort4*>(hi)[idx] = ushort4{hh[0], hh[1], hh[2], hh[3]};
    reinterpret_cast<ushort4*>(lo)[idx] = ushort4{ll[0], ll[1], ll[2], ll[3]};
}

// ---------------- combo1: split w0, split w1, prep(z -> p0 planes) ----------------
__global__ void combo1(const float* __restrict__ z, const float* __restrict__ w0,
                       const float* __restrict__ w1,
                       ushortT* __restrict__ p0h, ushortT* __restrict__ p0l,
                       ushortT* __restrict__ w0h, ushortT* __restrict__ w0l,
                       ushortT* __restrict__ w1h, ushortT* __restrict__ w1l, int N) {
    int b = blockIdx.x, tid = threadIdx.x;
    if (b < 256) {                       // w0: 65536 float4 items
        split_item(w0, w0h, w0l, b * 256 + tid);
        return;
    }
    if (b < 1280) {                      // w1: 262144 items
        split_item(w1, w1h, w1l, (b - 256) * 256 + tid);
        return;
    }
    // prep: one wave per 256-row
    int gw = (b - 1280) * 4 + (tid >> 6);
    int lane = tid & 63;
    if (gw >= N) return;
    float4 zv = reinterpret_cast<const float4*>(z + (size_t)gw * 256)[lane];
    float z0 = __shfl(zv.x, 0, 64);
    float x0 = fmaxf(z0, 1.f + EPSF);
    float d = acoshf(x0);
    float f = div_sinh_f(d);
    float vx = (lane == 0) ? 0.f : zv.x * f;
    float vy = zv.y * f, vz = zv.z * f, vw = zv.w * f;
    float ss = wred(vx * vx + vy * vy + vz * vz + vw * vw);
    float n = sqrtf(ss);
    float s = fminf(1.f, MAXN / fmaxf(n, EPSF));
    float o[4] = {vx * s, vy * s, vz * s, vw * s};
    ushortT hh[4], ll[4];
#pragma unroll
    for (int e = 0; e < 4; ++e) bsplit(o[e], hh[e], ll[e]);
    reinterpret_cast<ushort4*>(p0h + (size_t)gw * 256)[lane] = ushort4{hh[0], hh[1], hh[2], hh[3]};
    reinterpret_cast<ushort4*>(p0l + (size_t)gw * 256)[lane] = ushort4{ll[0], ll[1], ll[2], ll[3]};
}

// ---------------- rowscale (standalone, for s1) ----------------
__global__ void rowscale_kernel(const float* __restrict__ partials, float* __restrict__ scale,
                                int N, int nSlices) {
    int r = blockIdx.x * blockDim.x + threadIdx.x;
    if (r >= N) return;
    float s = 0.f;
    for (int k = 0; k < nSlices; ++k) s += partials[(size_t)k * N + r];
    float n = sqrtf(s);
    scale[r] = fminf(1.f, MAXN / fmaxf(n, EPSF));
}

// ---------------- combo2: rowscale(s2) + split w2 ----------------
__global__ void combo2(const float* __restrict__ partials, float* __restrict__ s2,
                       const float* __restrict__ w2,
                       ushortT* __restrict__ w2h, ushortT* __restrict__ w2l, int N) {
    int b = blockIdx.x, tid = threadIdx.x;
    if (b < 128) {
        int r = b * 256 + tid;
        if (r >= N) return;
        float s = 0.f;
        for (int k = 0; k < 16; ++k) s += partials[(size_t)k * N + r];
        float n = sqrtf(s);
        s2[r] = fminf(1.f, MAXN / fmaxf(n, EPSF));
        return;
    }
    split_item(w2, w2h, w2l, (b - 128) * 256 + tid);
}

// ---------------- 5-region prefetch-rotated 16x16 split-bf16 GEMM ----------------
// C[N x M] = (sA_r * A) @ W^T + bias. BM = IM*32, BN = 256, BK = 32. 8 waves 2(M) x 4(N).
// Region r issues ds_reads for region r+1's MFMA cluster -> LDS bursts overlap matrix bursts.
// Cross-wave DMA visibility: per-wave counted vmcnt BEFORE the shared barrier (X1 + tail).
// OUTMODE 0: bf16 hi/lo planes + partial row-sumsq. OUTMODE 2: fused Lorentz-final epilogue.
template<int OUTMODE, int IM>
__global__ __launch_bounds__(512, 2) void gemm_v8(
    const ushortT* __restrict__ Ah_g, const ushortT* __restrict__ Al_g,
    const ushortT* __restrict__ Wh_g, const ushortT* __restrict__ Wl_g,
    const float* __restrict__ bias, const float* __restrict__ scaleA,
    float* __restrict__ outF, ushortT* __restrict__ outH, ushortT* __restrict__ outL,
    float* __restrict__ partials, int K, int M, int nColBlk, int Nrows,
    const float* __restrict__ z_g, const float* __restrict__ alpha_p,
    const float* __restrict__ step_p)
{
    constexpr int BM = IM * 32;
    constexpr int AS = BM * 32;
    constexpr int BS = 256 * 32;
    constexpr int BUF = 2 * AS + 2 * BS;
    constexpr int HM = IM / 2;
    __shared__ __align__(16) ushortT lds[2 * BUF];

    const int tid = threadIdx.x;
    const int wid = tid >> 6, lane = tid & 63;
    const int nwg = gridDim.x;
    const int swz = ((int)blockIdx.x & 7) * (nwg >> 3) + ((int)blockIdx.x >> 3);
    const int rb = swz / nColBlk, cb = swz % nColBlk;
    const int rowBase = rb * BM, colBase = cb * 256;

    const int rl = tid >> 2;
    const int ks = (tid & 3) ^ ((rl >> 1) & 3);
    const int d8 = tid * 8;
    const ushortT* gAh0 = Ah_g + (size_t)(rowBase + rl) * K + ks * 8;
    const ushortT* gAl0 = Al_g + (size_t)(rowBase + rl) * K + ks * 8;
    const ushortT* gAh1 = Ah_g + (size_t)(rowBase + 128 + rl) * K + ks * 8;  // IM==8 only
    const ushortT* gAl1 = Al_g + (size_t)(rowBase + 128 + rl) * K + ks * 8;
    const ushortT* gBh0 = Wh_g + (size_t)(colBase + rl) * K + ks * 8;
    const ushortT* gBh1 = Wh_g + (size_t)(colBase + 128 + rl) * K + ks * 8;
    const ushortT* gBl0 = Wl_g + (size_t)(colBase + rl) * K + ks * 8;
    const ushortT* gBl1 = Wl_g + (size_t)(colBase + 128 + rl) * K + ks * 8;
#define STG(p, dst, nbo, nk) gload_lds16((p) + (nk), &lds[(nbo) + (dst) + d8])

    const int warpM = wid >> 2, warpN = wid & 3;
    const int frow = lane & 15, fk = lane >> 4;
    const int pslot8 = (fk ^ ((frow >> 1) & 3)) * 8;
    const int aoff = (warpM * (IM * 16) + frow) * 32 + pslot8;
    const int boff = (warpN * 64 + frow) * 32 + pslot8;

    f32_4 acc[IM][4];
#pragma unroll
    for (int i = 0; i < IM; ++i)
#pragma unroll
        for (int j = 0; j < 4; ++j) acc[i][j] = f32_4{0.f, 0.f, 0.f, 0.f};

    // prologue: stage tile 0 into buffer 0
    STG(gAh0, 0, 0, 0);
    if constexpr (IM == 8) STG(gAh1, 4096, 0, 0);
    STG(gAl0, AS, 0, 0);
    if constexpr (IM == 8) STG(gAl1, AS + 4096, 0, 0);
    STG(gBh0, 2 * AS, 0, 0); STG(gBh1, 2 * AS + 4096, 0, 0);
    STG(gBl0, 2 * AS + BS, 0, 0); STG(gBl1, 2 * AS + BS + 4096, 0, 0);
    asm volatile("s_waitcnt vmcnt(0)" ::: "memory");
    BAR;

    const int nt = K >> 5;
    for (int t = 0; t < nt; ++t) {
        const ushortT* lb = &lds[(t & 1) * BUF];
        const int nbo = ((t & 1) ^ 1) * BUF;
        const int nk = (t + 1) << 5;
        const bool more = (t + 1) < nt;
        bf16_8 ah[IM], bh[4], bl[4], al[IM];

        // ---- T-start: read ah[all], bh[all] (P0+P1 operands); stage Ah; MFMA P0;
        //      per-wave drain of Bl(t) rounds; BAR (publishes Bl for R1's reads) ----
#pragma unroll
        for (int i = 0; i < IM; ++i) ah[i] = *reinterpret_cast<const bf16_8*>(&lb[aoff + i * 512]);
#pragma unroll
        for (int j = 0; j < 4; ++j) bh[j] = *reinterpret_cast<const bf16_8*>(&lb[2 * AS + boff + j * 512]);
        if (more) { STG(gAh0, 0, nbo, nk); if constexpr (IM == 8) STG(gAh1, 4096, nbo, nk); }
        __builtin_amdgcn_s_setprio(1);
#pragma unroll
        for (int i = 0; i < HM; ++i)
#pragma unroll
            for (int j = 0; j < 4; ++j) acc[i][j] = MFMA16(ah[i], bh[j], acc[i][j], 0, 0, 0);
        __builtin_amdgcn_s_setprio(0);
        if (more) {
            if constexpr (IM == 8) asm volatile("s_waitcnt vmcnt(2)" ::: "memory");
            else                   asm volatile("s_waitcnt vmcnt(1)" ::: "memory");
        } else {
            asm volatile("s_waitcnt vmcnt(0)" ::: "memory");
        }
        BAR;

        // ---- R1: read bl (P2/P3 operands); stage Al; MFMA P1 ----
#pragma unroll
        for (int j = 0; j < 4; ++j) bl[j] = *reinterpret_cast<const bf16_8*>(&lb[2 * AS + BS + boff + j * 512]);
        if (more) { STG(gAl0, AS, nbo, nk); if constexpr (IM == 8) STG(gAl1, AS + 4096, nbo, nk); }
        __builtin_amdgcn_s_setprio(1);
#pragma unroll
        for (int i = HM; i < IM; ++i)
#pragma unroll
            for (int j = 0; j < 4; ++j) acc[i][j] = MFMA16(ah[i], bh[j], acc[i][j], 0, 0, 0);
        __builtin_amdgcn_s_setprio(0);
        BAR;

        // ---- R2: read al[0..HM) (P4 operands); stage Bh; MFMA P2 ----
#pragma unroll
        for (int i = 0; i < HM; ++i) al[i] = *reinterpret_cast<const bf16_8*>(&lb[AS + aoff + i * 512]);
        if (more) { STG(gBh0, 2 * AS, nbo, nk); STG(gBh1, 2 * AS + 4096, nbo, nk); }
        __builtin_amdgcn_s_setprio(1);
#pragma unroll
        for (int i = 0; i < HM; ++i)
#pragma unroll
            for (int j = 0; j < 4; ++j) acc[i][j] = MFMA16(ah[i], bl[j], acc[i][j], 0, 0, 0);
        __builtin_amdgcn_s_setprio(0);
        BAR;

        // ---- R3: read al[HM..IM) (P5 operands); stage Bl; MFMA P3 ----
#pragma unroll
        for (int i = HM; i < IM; ++i) al[i] = *reinterpret_cast<const bf16_8*>(&lb[AS + aoff + i * 512]);
        if (more) { STG(gBl0, 2 * AS + BS, nbo, nk); STG(gBl1, 2 * AS + BS + 4096, nbo, nk); }
        __builtin_amdgcn_s_setprio(1);
#pragma unroll
        for (int i = HM; i < IM; ++i)
#pragma unroll
            for (int j = 0; j < 4; ++j) acc[i][j] = MFMA16(ah[i], bl[j], acc[i][j], 0, 0, 0);
        __builtin_amdgcn_s_setprio(0);
        BAR;

        // ---- R4: MFMA P4 + P5 (pure matrix burst); tail counted drain; tile BAR ----
        __builtin_amdgcn_s_setprio(1);
#pragma unroll
        for (int i = 0; i < HM; ++i)
#pragma unroll
            for (int j = 0; j < 4; ++j) acc[i][j] = MFMA16(al[i], bh[j], acc[i][j], 0, 0, 0);
#pragma unroll
        for (int i = HM; i < IM; ++i)
#pragma unroll
            for (int j = 0; j < 4; ++j) acc[i][j] = MFMA16(al[i], bh[j], acc[i][j], 0, 0, 0);
        __builtin_amdgcn_s_setprio(0);
        asm volatile("s_waitcnt vmcnt(2)" ::: "memory");
        BAR;
    }
#undef STG

    // ---------------- epilogue ----------------
    const int cbase = colBase + warpN * 64 + frow;
    if constexpr (OUTMODE == 0) {
        float bv[4];
#pragma unroll
        for (int j = 0; j < 4; ++j) bv[j] = bias[cbase + j * 16];
        const size_t slice = (size_t)(cb * 4 + warpN) * Nrows;
#pragma unroll
        for (int i = 0; i < IM; ++i) {
            const int row0 = rowBase + warpM * (IM * 16) + i * 16 + fk * 4;
            float4 sa4 = float4{1.f, 1.f, 1.f, 1.f};
            if (scaleA) sa4 = *reinterpret_cast<const float4*>(&scaleA[row0]);
            float psum[4];
#pragma unroll
            for (int r = 0; r < 4; ++r) {
                const float sa = reinterpret_cast<const float*>(&sa4)[r];
                const int row = row0 + r;
                const size_t base = (size_t)row * M;
                float ssv = 0.f;
#pragma unroll
                for (int j = 0; j < 4; ++j) {
                    float y = sa * acc[i][j][r] + bv[j];
                    if (j == 0 && cbase == 0) y = 0.f;
                    ushortT h, l;
                    bsplit(y, h, l);
                    outH[base + cbase + j * 16] = h;
                    outL[base + cbase + j * 16] = l;
                    ssv += y * y;
                }
                psum[r] = red16(ssv);
            }
            if (frow == 0) {
#pragma unroll
                for (int r = 0; r < 4; ++r) partials[slice + row0 + r] = psum[r];
            }
        }
    }
    if constexpr (OUTMODE == 2) {
        // fused Lorentz-final chain. colBase==0, M==256, BM==128 (IM==4).
        float* red  = (float*)&lds[0];
        float* bufZ = red;              // [128]
        float* bufA = red + 128;        // [128][4]
        float* bufB = red + 640;        // [128][8]
        float* bufC = red + 1664;       // [128][4]
        float* bufD = red + 2176;       // [128][4]
        const float stepv = 1.f / (1.f + expf(-step_p[0]));
        const float av    = 1.f / (1.f + expf(-alpha_p[0]));
        const int cb0 = warpN * 64 + frow;
        const bool c0own = (cb0 == 0);
        float bv[4];
#pragma unroll
        for (int j = 0; j < 4; ++j) bv[j] = bias[cb0 + j * 16];
        BAR;
#pragma unroll
        for (int ig = 0; ig < 2; ++ig) {
            float yv[2][4][4], zz[2][4][4], z0[2][4], st0[2][4];
#pragma unroll
            for (int ii = 0; ii < 2; ++ii) {
                const int i = ig * 2 + ii;
                const int row0 = warpM * 64 + i * 16 + fk * 4;
                float4 sa4 = float4{1.f, 1.f, 1.f, 1.f};
                if (scaleA) sa4 = *reinterpret_cast<const float4*>(&scaleA[rowBase + row0]);
#pragma unroll
                for (int rr = 0; rr < 4; ++rr) {
                    const float sa = reinterpret_cast<const float*>(&sa4)[rr];
                    const size_t gz = (size_t)(rowBase + row0 + rr) * 256 + cb0;
#pragma unroll
                    for (int j = 0; j < 4; ++j) {
                        yv[ii][j][rr] = sa * acc[i][j][rr] + bv[j];
                        zz[ii][j][rr] = z_g[gz + j * 16];
                    }
                }
            }
            // R1: ssq of v_transformed (cols >= 1); publish z0
#pragma unroll
            for (int ii = 0; ii < 2; ++ii) {
                const int row0 = warpM * 64 + (ig * 2 + ii) * 16 + fk * 4;
#pragma unroll
                for (int rr = 0; rr < 4; ++rr) {
                    float p = 0.f;
#pragma unroll
                    for (int j = 0; j < 4; ++j) {
                        float yq = (c0own && j == 0) ? 0.f : yv[ii][j][rr];
                        p += yq * yq;
                    }
                    p = red16(p);
                    if (frow == 0) bufA[(row0 + rr) * 4 + warpN] = p;
                    if (c0own) bufZ[row0 + rr] = zz[ii][0][rr];
                }
            }
            BAR;
            // e = cosh(m)*z + sinh_div*sc*vf  (into yv); partials e^2, z*e
#pragma unroll
            for (int ii = 0; ii < 2; ++ii) {
                const int row0 = warpM * 64 + (ig * 2 + ii) * 16 + fk * 4;
#pragma unroll
                for (int rr = 0; rr < 4; ++rr) {
                    const int rw = row0 + rr;
                    float ss2 = bufA[rw * 4] + bufA[rw * 4 + 1] + bufA[rw * 4 + 2] + bufA[rw * 4 + 3];
                    z0[ii][rr] = bufZ[rw];
                    float n2 = sqrtf(ss2);
                    float k1 = fminf(1.f, MAXN / fmaxf(n2, EPSF)) * stepv;
                    float n  = k1 * n2;
                    float scv = fminf(1.f, MAXN / fmaxf(n, EPSF));
                    float m  = fminf(n, MAXN);
                    float ch = coshf(m), sdv = sinh_div_f(m);
                    float pe = 0.f, pz = 0.f;
#pragma unroll
                    for (int j = 0; j < 4; ++j) {
                        float vf = (c0own && j == 0) ? 0.f : yv[ii][j][rr] * k1;
                        float e  = ch * zz[ii][j][rr] + sdv * scv * vf;
                        yv[ii][j][rr] = e;
                        if (!(c0own && j == 0)) { pe += e * e; pz += zz[ii][j][rr] * e; }
                    }
                    pe = red16(pe); pz = red16(pz);
                    if (frow == 0) { bufB[rw * 8 + warpN * 2] = pe; bufB[rw * 8 + warpN * 2 + 1] = pz; }
                }
            }
            BAR;
            // logmap: st = oa*(e + ip*z) (into yv); partials st^2
#pragma unroll
            for (int ii = 0; ii < 2; ++ii) {
                const int row0 = warpM * 64 + (ig * 2 + ii) * 16 + fk * 4;
#pragma unroll
                for (int rr = 0; rr < 4; ++rr) {
                    const int rw = row0 + rr;
                    float r3 = bufB[rw * 8] + bufB[rw * 8 + 2] + bufB[rw * 8 + 4] + bufB[rw * 8 + 6];
                    float r4 = bufB[rw * 8 + 1] + bufB[rw * 8 + 3] + bufB[rw * 8 + 5] + bufB[rw * 8 + 7];
                    float u0 = sqrtf(1.f + r3);
                    float ip = fminf(r4 - z0[ii][rr] * u0, -(1.f + EPSF));
                    float dd = acoshf(-ip);
                    float g = div_sinh_f(dd);
                    float oa = (1.f - av) * g;
                    st0[ii][rr] = oa * (u0 + ip * z0[ii][rr]);
                    float p5 = 0.f;
#pragma unroll
                    for (int j = 0; j < 4; ++j) {
                        float st = oa * (yv[ii][j][rr] + ip * zz[ii][j][rr]);
                        yv[ii][j][rr] = st;
                        if (!(c0own && j == 0)) p5 += st * st;
                    }
                    p5 = red16(p5);
                    if (frow == 0) bufC[rw * 4 + warpN] = p5;
                }
            }
            BAR;
            // expmap: f = ch5*z + sd5*s5*st (into yv); partials f^2
#pragma unroll
            for (int ii = 0; ii < 2; ++ii) {
                const int row0 = warpM * 64 + (ig * 2 + ii) * 16 + fk * 4;
#pragma unroll
                for (int rr = 0; rr < 4; ++rr) {
                    const int rw = row0 + rr;
                    float r5 = bufC[rw * 4] + bufC[rw * 4 + 1] + bufC[rw * 4 + 2] + bufC[rw * 4 + 3];
                    float vv2 = r5 - st0[ii][rr] * st0[ii][rr];
                    float n5 = sqrtf(fmaxf(vv2, 0.f));
                    float s5 = fminf(1.f, MAXN / fmaxf(n5, EPSF));
                    float m5 = fminf(n5, MAXN);
                    float ch5 = coshf(m5), sd5 = sinh_div_f(m5);
                    float p6 = 0.f;
#pragma unroll
                    for (int j = 0; j < 4; ++j) {
                        float f = ch5 * zz[ii][j][rr] + sd5 * s5 * yv[ii][j][rr];
                        yv[ii][j][rr] = f;
                        if (!(c0own && j == 0)) p6 += f * f;
                    }
                    p6 = red16(p6);
                    if (frow == 0) bufD[rw * 4 + warpN] = p6;
                }
            }
            BAR;
            // projx + store z_next and z_h copy
#pragma unroll
            for (int ii = 0; ii < 2; ++ii) {
                const int row0 = warpM * 64 + (ig * 2 + ii) * 16 + fk * 4;
#pragma unroll
                for (int rr = 0; rr < 4; ++rr) {
                    const int rw = row0 + rr;
                    float r6 = bufD[rw * 4] + bufD[rw * 4 + 1] + bufD[rw * 4 + 2] + bufD[rw * 4 + 3];
                    float zn0 = sqrtf(1.f + r6);
                    const size_t rowG = (size_t)(rowBase + rw);
#pragma unroll
                    for (int j = 0; j < 4; ++j) {
                        const int col = cb0 + j * 16;
                        float v = (c0own && j == 0) ? zn0 : yv[ii][j][rr];
                        outF[rowG * 256 + col] = v;
                        outF[((size_t)Nrows + rowG) * 256 + col] = zz[ii][j][rr];
                    }
                }
            }
        }
    }
}

extern "C" void kernel_launch(void* const* d_in, const int* in_sizes, int n_in,
                              void* d_out, int out_size, void* d_ws, size_t ws_size,
                              hipStream_t stream) {
    const float* z_h  = (const float*)d_in[0];
    const float* w0   = (const float*)d_in[1];
    const float* b0   = (const float*)d_in[2];
    const float* w1   = (const float*)d_in[3];
    const float* b1   = (const float*)d_in[4];
    const float* w2   = (const float*)d_in[5];
    const float* b2   = (const float*)d_in[6];
    const float* alph = (const float*)d_in[7];
    const float* stps = (const float*)d_in[8];
    float* out = (float*)d_out;

    const int D = 256, H = 1024;
    const int N = in_sizes[0] / D;   // 32768

    // ---- d_out slot1 [0,32MB): p0 planes (dead after GEMM0; slot1 written by GEMM2 epi) ----
    char* ob = (char*)d_out;
    ushortT* p0h = (ushortT*)ob;                       // 16 MB
    ushortT* p0l = (ushortT*)(ob + 16777216);          // 16 MB
    // ---- d_out slot2 [32,64MB) scratch (all dead before GEMM2 epilogue writes the copy) ----
    char* s2b = ob + 33554432;
    ushortT* w0h = (ushortT*)(s2b);                    // 512 KB
    ushortT* w0l = (ushortT*)(s2b + 524288);
    ushortT* w1h = (ushortT*)(s2b + 1048576);          // 2 MB
    ushortT* w1l = (ushortT*)(s2b + 3145728);
    float* partials = (float*)(s2b + 5242880);         // 2 MB (16 x N)
    float* s1 = (float*)(s2b + 7340032);               // 128 KB

    // ---- d_ws: activation plane pairs; paH region reused for w2/s2 after GEMM1 ----
    ushortT* paH = (ushortT*)d_ws;                     // 64 MB
    ushortT* paL = paH + (size_t)N * H;                // 64 MB
    ushortT* pbH = paL + (size_t)N * H;                // 64 MB
    ushortT* pbL = pbH + (size_t)N * H;                // 64 MB
    ushortT* w2h = (ushortT*)d_ws;                     // 512 KB (written after GEMM1)
    ushortT* w2l = (ushortT*)((char*)d_ws + 524288);   // 512 KB
    float* s2 = (float*)((char*)d_ws + 1048576);       // 128 KB

    // split w0/w1 + prep
    combo1<<<1280 + N / 4, 256, 0, stream>>>(z_h, w0, w1, p0h, p0l, w0h, w0l, w1h, w1l, N);

    // GEMM0: y0 planes = prep @ W0^T + b0
    gemm_v8<0, 8><<<(N / 256) * (H / 256), 512, 0, stream>>>(
        p0h, p0l, w0h, w0l, b0, nullptr, nullptr, paH, paL, partials, D, H, H / 256, N,
        nullptr, nullptr, nullptr);
    rowscale_kernel<<<(N + 255) / 256, 256, 0, stream>>>(partials, s1, N, 16);

    // GEMM1: y1 planes = (s1*y0) @ W1^T + b1
    gemm_v8<0, 8><<<(N / 256) * (H / 256), 512, 0, stream>>>(
        paH, paL, w1h, w1l, b1, s1, nullptr, pbH, pbL, partials, H, H, H / 256, N,
        nullptr, nullptr, nullptr);

    // rowscale s2 + split w2 (into now-dead paH region)
    combo2<<<384, 256, 0, stream>>>(partials, s2, w2, w2h, w2l, N);

    // GEMM2 + fused Lorentz-final chain -> writes both output slots
    gemm_v8<2, 4><<<(N / 128) * (D / 256), 512, 0, stream>>>(
        pbH, pbL, w2h, w2l, b2, s2, out, nullptr, nullptr, nullptr, H, D, D / 256, N,
        z_h, alph, stps);
}